// Round 7
// baseline (635.155 us; speedup 1.0000x reference)
//
#include <hip/hip_runtime.h>

typedef unsigned short u16;
typedef unsigned int u32;
typedef __attribute__((ext_vector_type(8))) short s16x8;   // 8 bf16 (4 VGPRs)
typedef __attribute__((ext_vector_type(4))) float f32x4;

__device__ __forceinline__ float bf2f(u16 u) { return __uint_as_float(((u32)u) << 16); }
__device__ __forceinline__ u16 f2bf(float f) {
    u32 b = __float_as_uint(f);
    b += 0x7fffu + ((b >> 16) & 1u);
    return (u16)(b >> 16);
}

__global__ void probe_mark(float* __restrict__ out, int n, float val) {
    int i = blockIdx.x * blockDim.x + threadIdx.x;
    if (i < n) out[i] = val;
}

// ---------------- merged prep: zero cnt/cur + weight convert + att projections ----------------
// blocks [0, nzb)            : zero cnt+cur (zc u32s)
// blocks [nzb, nzb+768)      : wt[(w*256+c)*128+k] = bf16(w<5 ? Ws[w][k][c] : W_res[k][c])
// blocks [nzb+768, nzb+774)  : w_d_all / w_s_cat / bias_sum reductions
__global__ void k_prep_all(const float* __restrict__ Ws, const float* __restrict__ W_res,
                           const float* __restrict__ att_src, const float* __restrict__ att_dst,
                           const float* __restrict__ biases,
                           u32* __restrict__ cnt, int zc, int nzb, u16* __restrict__ wt,
                           float* __restrict__ w_d_all, float* __restrict__ w_s_cat,
                           float* __restrict__ bias_sum) {
    int b = blockIdx.x;
    if (b < nzb) {
        int i = b * 256 + threadIdx.x;
        if (i < zc) cnt[i] = 0u;
        return;
    }
    b -= nzb;
    if (b < 768) {                      // 768*256 == 6*256*128 exactly
        int i = b * 256 + threadIdx.x;
        int k = i & 127;
        int c = (i >> 7) & 255;
        int w = i >> 15;
        float v = (w < 5) ? Ws[(size_t)w * 32768 + k * 256 + c] : W_res[k * 256 + c];
        wt[i] = f2bf(v);
        return;
    }
    b -= 768;
    if (b < 5) {
        int k = threadIdx.x;
        if (k >= 128) return;
        const float* Wr = Ws + (size_t)b * 128 * 256 + (size_t)k * 256;
        for (int h = 0; h < 4; ++h) {
            float ss = 0.f, sd = 0.f;
            for (int c = 0; c < 64; ++c) {
                float w = Wr[h * 64 + c];
                ss += w * att_src[(b * 4 + h) * 64 + c];
                sd += w * att_dst[(b * 4 + h) * 64 + c];
            }
            w_d_all[k * 20 + b * 4 + h] = sd;
            w_s_cat[b * 512 + k * 4 + h] = ss;
        }
    } else if (threadIdx.x < 256) {
        float s = 0.f;
        for (int r = 0; r < 5; ++r) s += biases[r * 256 + threadIdx.x];
        bias_sum[threadIdx.x] = s;
    }
}

// ---------------- merged skinny GEMMs (a_s / a_d projections) ----------------
struct SDesc { const float* A; const float* W; float* out; int N; int Kout; int start; };
struct STab { SDesc d[6]; int total; };

__global__ void skinny_all(STab T) {
    int idx = blockIdx.x * blockDim.x + threadIdx.x;
    if (idx >= T.total) return;
    int mi = 0;
#pragma unroll
    for (int i = 1; i < 6; ++i) if (idx >= T.d[i].start) mi = i;
    SDesc d = T.d[mi];
    int local = idx - d.start;
    int row = local / d.Kout, col = local - row * d.Kout;
    const float* a = d.A + (size_t)row * 128;
    float s = 0.f;
    for (int k = 0; k < 128; ++k) s += a[k] * d.W[k * d.Kout + col];
    d.out[(size_t)row * d.Kout + col] = s;
}

// ---------------- merged MFMA GEMMs — register-direct (R7 rewrite) ----------------
// R6 version staged A into LDS once per 64-col strip (blockIdx.y=4) -> A read+converted 4x
// (~330MB) + 2 barriers. Now: 1-D grid, each block = 64 rows x all 256 cols; each wave owns
// 16 rows. A fragments load straight from global fp32 (once), B fragments straight from wt
// (384KB total, L2-hot; identical per-lane addresses to the old sB reads). No LDS, no syncs.
struct GDesc { const float* A; u16* C; int wslice; int N; int start; };
struct GTab { GDesc d[6]; };

__global__ __launch_bounds__(256) void gemm_all(GTab T, const u16* __restrict__ wt) {
    int bx = blockIdx.x;
    int mi = 0;
#pragma unroll
    for (int i = 1; i < 6; ++i) if (bx >= T.d[i].start) mi = i;
    GDesc d = T.d[mi];
    int R0 = (bx - d.start) * 64;
    int t = threadIdx.x;
    int wave = t >> 6, lane = t & 63;
    int quad = lane >> 4, m = lane & 15;

    // A operand row for this lane (free index = m), 32 floats -> 4 bf16x8 fragments
    int arow = R0 + wave * 16 + m;
    s16x8 af[4];
    if (arow < d.N) {
        const float* ar = d.A + (size_t)arow * 128 + quad * 8;
#pragma unroll
        for (int k0 = 0; k0 < 4; ++k0) {
            float4 v0 = *(const float4*)(ar + k0 * 32);
            float4 v1 = *(const float4*)(ar + k0 * 32 + 4);
            s16x8 a;
            a[0] = (short)f2bf(v0.x); a[1] = (short)f2bf(v0.y);
            a[2] = (short)f2bf(v0.z); a[3] = (short)f2bf(v0.w);
            a[4] = (short)f2bf(v1.x); a[5] = (short)f2bf(v1.y);
            a[6] = (short)f2bf(v1.z); a[7] = (short)f2bf(v1.w);
            af[k0] = a;
        }
    } else {
#pragma unroll
        for (int k0 = 0; k0 < 4; ++k0) af[k0] = (s16x8){0, 0, 0, 0, 0, 0, 0, 0};
    }

    // B operand: col = ct*16 + m; per-lane addr = wt[slice][(ct*16+m)][k0*32 + quad*8]
    const u16* wb = wt + (size_t)d.wslice * 32768 + (size_t)m * 128 + quad * 8;
#pragma unroll
    for (int ct = 0; ct < 16; ++ct) {
        const u16* wc = wb + (size_t)ct * 16 * 128;
        f32x4 acc = {};
#pragma unroll
        for (int k0 = 0; k0 < 4; ++k0) {
            s16x8 bf = *(const s16x8*)(wc + k0 * 32);
            acc = __builtin_amdgcn_mfma_f32_16x16x32_bf16(af[k0], bf, acc, 0, 0, 0);
        }
        // C/D: col = lane&15, row = (lane>>4)*4 + i
#pragma unroll
        for (int i = 0; i < 4; ++i) {
            int srow = R0 + wave * 16 + quad * 4 + i;
            if (srow < d.N) d.C[(size_t)srow * 256 + ct * 16 + m] = f2bf(acc[i]);
        }
    }
}

// ---------------- (row,rel)-segmented CSR build over all 5 relations ----------------
struct EdgeP { const int* src[5]; const int* dst[5]; int base[5]; };

__global__ void k_count(EdgeP P, u32* __restrict__ cnt, int E) {
    int r = blockIdx.y;
    int e = blockIdx.x * blockDim.x + threadIdx.x;
    if (e >= E) return;
    atomicAdd(cnt + (size_t)P.dst[r][e] * 5 + r, 1u);
}

__global__ void k_scan1(const u32* __restrict__ cnt, u32* __restrict__ off,
                        u32* __restrict__ bsum, int nblk) {
    int b = blockIdx.x, t = threadIdx.x;
    size_t base = (size_t)b * 1024 + t * 4;
    u32 v0 = cnt[base], v1 = cnt[base + 1], v2 = cnt[base + 2], v3 = cnt[base + 3];
    u32 tsum = v0 + v1 + v2 + v3;
    __shared__ u32 s[256];
    u32 x = tsum;
    s[t] = x; __syncthreads();
    for (int ofs = 1; ofs < 256; ofs <<= 1) {
        u32 y = (t >= ofs) ? s[t - ofs] : 0u;
        __syncthreads();
        x += y; s[t] = x;
        __syncthreads();
    }
    u32 ex = x - tsum;
    off[base] = ex; off[base + 1] = ex + v0; off[base + 2] = ex + v0 + v1; off[base + 3] = ex + v0 + v1 + v2;
    if (t == 255) bsum[b] = x;
}

__global__ void k_scan2(u32* __restrict__ bsum, int nblk) {
    __shared__ u32 s[512];
    __shared__ u32 carry_s;
    int t = threadIdx.x;
    if (t == 0) carry_s = 0;
    __syncthreads();
    for (int c0 = 0; c0 < nblk; c0 += 512) {
        int i = c0 + t;
        u32 v = (i < nblk) ? bsum[i] : 0u;
        u32 x = v;
        s[t] = x; __syncthreads();
        for (int ofs = 1; ofs < 512; ofs <<= 1) {
            u32 y = (t >= ofs) ? s[t - ofs] : 0u;
            __syncthreads();
            x += y; s[t] = x;
            __syncthreads();
        }
        u32 carry = carry_s;
        if (i < nblk) bsum[i] = x - v + carry;
        __syncthreads();
        if (t == 511) carry_s = carry + x;
        __syncthreads();
    }
}

__global__ void k_scan3(u32* __restrict__ off, const u32* __restrict__ bsum, int nblk) {
    int b = blockIdx.x, t = threadIdx.x;
    u32 add = bsum[b];
    size_t base = (size_t)b * 1024 + t * 4;
    off[base] += add; off[base + 1] += add; off[base + 2] += add; off[base + 3] += add;
}

__global__ void k_fill(EdgeP P, const u32* __restrict__ off, u32* __restrict__ cur,
                       u32* __restrict__ epay, int E) {
    int r = blockIdx.y;
    int e = blockIdx.x * blockDim.x + threadIdx.x;
    if (e >= E) return;
    int d = P.dst[r][e];
    size_t slot = (size_t)d * 5 + r;
    u32 pos = off[slot] + atomicAdd(cur + slot, 1u);
    epay[pos] = (u32)(P.base[r] + P.src[r][e]);
}

// ---------------- fused gather (single pass + wave-coop payload preload) --------------
// R6 PMC: VALUBusy=51%, hbm=34%, occ=75% -> latency-bound on the per-edge dependent
// chain epay[e] -> as/hs loads. A row's edges are CONTIGUOUS (o0..o5, avg 12.5, <64
// essentially always), so one cooperative load epay[o0+lane] puts every payload in the
// wave's registers; per-edge fetch becomes __shfl (ALU, no memory hop). i>=64 tail
// falls back to a direct load (wave-uniform branch). 512-thread blocks for occupancy.
__global__ __launch_bounds__(512) void k_gather(
        const u32* __restrict__ offs, const u32* __restrict__ epay,
        const float* __restrict__ as_h,   // as_cat: [gsrc][4 heads]
        const float* __restrict__ a_d,    // [row][rel*4+h]
        const u16* __restrict__ hs, const u16* __restrict__ resb,
        const float* __restrict__ bias_sum,
        const float* __restrict__ gamma, const float* __restrict__ beta,
        float* __restrict__ out, int NJ) {
    int row = blockIdx.x * 8 + (threadIdx.x >> 6);
    int lane = threadIdx.x & 63;
    if (row >= NJ) return;

    // hoisted epilogue loads — hide under the gather
    ushort4 rr = *(const ushort4*)(resb + (size_t)row * 256 + lane * 4);
    float4 bb = *(const float4*)(bias_sum + lane * 4);
    int c = lane * 4;
    float4 g = *(const float4*)(gamma + c);
    float4 be = *(const float4*)(beta + c);

    int hd = lane >> 4;                        // this lane's head (0..3)
    u32 hoff = (u32)(lane << 2);               // u16-elem offset within an hs row

    const float* adb = a_d + (size_t)row * 20 + hd;
    float adx[5] = { adb[0], adb[4], adb[8], adb[12], adb[16] };

    const u32* op = offs + (size_t)row * 5;
    u32 o[6];
#pragma unroll
    for (int i = 0; i < 6; ++i) o[i] = op[i];
    u32 deg = o[5] - o[0];

    // cooperative payload preload: lane L holds epay[o0+L] (covers rows with deg<=64)
    u32 pv = 0;
    if (deg) {
        u32 li = (u32)lane < deg ? (u32)lane : 0u;
        pv = epay[o[0] + li];
    }

    float a0 = 0.f, a1 = 0.f, a2 = 0.f, a3 = 0.f;
#pragma unroll
    for (int r = 0; r < 5; ++r) {              // rel is a compile-time constant
        float adr = adx[r];
        float n0 = 0.f, n1 = 0.f, n2 = 0.f, n3 = 0.f, dsum = 0.f;
        for (u32 e = o[r]; e < o[r + 1]; ++e) {
            u32 i = e - o[0];
            u32 p;
            if (i < 64u) p = __shfl(pv, (int)i);   // wave-uniform condition
            else         p = epay[e];
            float x = as_h[p * 4 + (u32)hd] + adr;
            x = x > 0.f ? x : 0.2f * x;
            float w = __expf(x);
            dsum += w;
            ushort4 hv = *(const ushort4*)(hs + ((size_t)p << 8) + hoff);
            n0 += w * bf2f(hv.x); n1 += w * bf2f(hv.y);
            n2 += w * bf2f(hv.z); n3 += w * bf2f(hv.w);
        }
        float iv = 1.f / (dsum + 1e-16f);      // empty segment: contributes 0, safe
        a0 += n0 * iv; a1 += n1 * iv; a2 += n2 * iv; a3 += n3 * iv;
    }

    float h0 = fmaxf(a0 + bf2f(rr.x) + bb.x, 0.f);
    float h1 = fmaxf(a1 + bf2f(rr.y) + bb.y, 0.f);
    float h2 = fmaxf(a2 + bf2f(rr.z) + bb.z, 0.f);
    float h3 = fmaxf(a3 + bf2f(rr.w) + bb.w, 0.f);
    float s = h0 + h1 + h2 + h3;
    float s2 = h0 * h0 + h1 * h1 + h2 * h2 + h3 * h3;
    for (int o2 = 32; o2; o2 >>= 1) {
        s += __shfl_xor(s, o2);
        s2 += __shfl_xor(s2, o2);
    }
    float mu = s * (1.f / 256.f);
    float var = s2 * (1.f / 256.f) - mu * mu;
    float rs = rsqrtf(var + 1e-5f);
    float4 o4;
    o4.x = (h0 - mu) * rs * g.x + be.x;
    o4.y = (h1 - mu) * rs * g.y + be.y;
    o4.z = (h2 - mu) * rs * g.z + be.z;
    o4.w = (h3 - mu) * rs * g.w + be.w;
    *(float4*)(out + (size_t)row * 256 + c) = o4;
}

// ---------------------------------------------------------------------------
static size_t align256(size_t x) { return (x + 255) & ~(size_t)255; }

extern "C" void kernel_launch(void* const* d_in, const int* in_sizes, int n_in,
                              void* d_out, int out_size, void* d_ws, size_t ws_size,
                              hipStream_t stream) {
    float* out = (float*)d_out;

    int NJ = in_sizes[0] / 128, NS = in_sizes[1] / 128, NM = in_sizes[2] / 128, NR = in_sizes[3] / 128;
    int E = in_sizes[4];
    bool cfg_ok = (n_in >= 21) && (out_size == NJ * 256)
        && (in_sizes[14] == 5 * 128 * 256) && (in_sizes[18] == 128 * 256)
        && (in_sizes[19] == 256) && (in_sizes[20] == 256);
    if (!cfg_ok) { probe_mark<<<8, 256, 0, stream>>>(out, 2048, 1000000.0f); return; }

    const float* x_job = (const float*)d_in[0];
    const float* x_st  = (const float*)d_in[1];
    const float* x_ma  = (const float*)d_in[2];
    const float* x_ro  = (const float*)d_in[3];
    EdgeP EP;
    EP.src[0] = (const int*)d_in[4];  EP.dst[0] = (const int*)d_in[5];
    EP.src[1] = (const int*)d_in[6];  EP.dst[1] = (const int*)d_in[7];
    EP.src[2] = (const int*)d_in[8];  EP.dst[2] = (const int*)d_in[9];
    EP.src[3] = (const int*)d_in[10]; EP.dst[3] = (const int*)d_in[11];
    EP.src[4] = (const int*)d_in[12]; EP.dst[4] = (const int*)d_in[13];
    EP.base[0] = 0; EP.base[1] = NS; EP.base[2] = 2 * NS;
    EP.base[3] = 2 * NS + NM; EP.base[4] = 2 * NS + 2 * NM;
    const float* Ws      = (const float*)d_in[14];
    const float* att_src = (const float*)d_in[15];
    const float* att_dst = (const float*)d_in[16];
    const float* biases  = (const float*)d_in[17];
    const float* W_res   = (const float*)d_in[18];
    const float* gamma   = (const float*)d_in[19];
    const float* beta    = (const float*)d_in[20];

    // (row,rel)-segmented CSR: 5*NJ counters, padded to scan granularity (1024)
    int nseg = 5 * NJ;
    int nblk = (nseg + 1023) / 1024;
    int NPAD = nblk * 1024;
    int TOT = 2 * NS + 2 * NM + NR;   // concatenated source-node count

    // --- workspace layout ---
    char* base = (char*)d_ws;
    size_t ob = 0;
    float*  w_d_all  = (float*)(base + ob);  ob += align256(128 * 20 * 4);
    float*  w_s_cat  = (float*)(base + ob);  ob += align256(5 * 128 * 4 * 4);
    float*  bias_sum = (float*)(base + ob);  ob += align256(256 * 4);
    float*  a_d      = (float*)(base + ob);  ob += align256((size_t)NJ * 20 * 4);
    float*  as_cat   = (float*)(base + ob);  ob += align256((size_t)TOT * 4 * 4);
    u16*    wt       = (u16*)(base + ob);    ob += align256((size_t)6 * 256 * 128 * 2);
    u16*    resb     = (u16*)(base + ob);    ob += align256((size_t)NJ * 256 * 2);
    u16*    hs_cat   = (u16*)(base + ob);    ob += align256((size_t)TOT * 256 * 2);
    u32*    cnt      = (u32*)(base + ob);    ob += align256((size_t)NPAD * 4);
    u32*    cur      = (u32*)(base + ob);    ob += align256((size_t)NPAD * 4);
    u32*    offs     = (u32*)(base + ob);    ob += align256((size_t)NPAD * 4);
    u32*    bsum     = (u32*)(base + ob);    ob += align256((size_t)nblk * 4);
    u32*    epay     = (u32*)(base + ob);    ob += align256((size_t)5 * E * 4);

    if (ws_size < ob) { probe_mark<<<8, 256, 0, stream>>>(out, 2048, 500000.0f); return; }

    // --- merged prep: zero cnt+cur, convert weights, att projections (1 launch) ---
    int zc = 2 * NPAD;
    int nzb = (zc + 255) / 256;
    k_prep_all<<<nzb + 768 + 6, 256, 0, stream>>>(Ws, W_res, att_src, att_dst, biases,
                                                  cnt, zc, nzb, wt,
                                                  w_d_all, w_s_cat, bias_sum);

    // --- merged skinny GEMMs (a_d: NJ x 20, a_s: per-relation N x 4 into as_cat) ---
    STab ST;
    int st = 0;
    ST.d[0] = {x_job, w_d_all,           a_d,                             NJ, 20, st}; st += NJ * 20;
    ST.d[1] = {x_st,  w_s_cat + 0 * 512, as_cat + (size_t)EP.base[0] * 4, NS, 4, st}; st += NS * 4;
    ST.d[2] = {x_st,  w_s_cat + 1 * 512, as_cat + (size_t)EP.base[1] * 4, NS, 4, st}; st += NS * 4;
    ST.d[3] = {x_ma,  w_s_cat + 2 * 512, as_cat + (size_t)EP.base[2] * 4, NM, 4, st}; st += NM * 4;
    ST.d[4] = {x_ma,  w_s_cat + 3 * 512, as_cat + (size_t)EP.base[3] * 4, NM, 4, st}; st += NM * 4;
    ST.d[5] = {x_ro,  w_s_cat + 4 * 512, as_cat + (size_t)EP.base[4] * 4, NR, 4, st}; st += NR * 4;
    ST.total = st;
    skinny_all<<<(ST.total + 255) / 256, 256, 0, stream>>>(ST);

    // --- merged MFMA GEMMs (register-direct, 1-D grid) ---
    int tJ = (NJ + 63) / 64, tS = (NS + 63) / 64, tM = (NM + 63) / 64, tR = (NR + 63) / 64;
    GTab GT;
    int gs = 0;
    GT.d[0] = {x_job, resb,                               5, NJ, gs}; gs += tJ;
    GT.d[1] = {x_st,  hs_cat + (size_t)EP.base[0] * 256,  0, NS, gs}; gs += tS;
    GT.d[2] = {x_st,  hs_cat + (size_t)EP.base[1] * 256,  1, NS, gs}; gs += tS;
    GT.d[3] = {x_ma,  hs_cat + (size_t)EP.base[2] * 256,  2, NM, gs}; gs += tM;
    GT.d[4] = {x_ma,  hs_cat + (size_t)EP.base[3] * 256,  3, NM, gs}; gs += tM;
    GT.d[5] = {x_ro,  hs_cat + (size_t)EP.base[4] * 256,  4, NR, gs}; gs += tR;
    gemm_all<<<gs, 256, 0, stream>>>(GT, wt);

    // --- (row,rel)-segmented CSR build ---
    k_count<<<dim3((E + 255) / 256, 5), 256, 0, stream>>>(EP, cnt, E);
    k_scan1<<<nblk, 256, 0, stream>>>(cnt, offs, bsum, nblk);
    k_scan2<<<1, 512, 0, stream>>>(bsum, nblk);
    k_scan3<<<nblk, 256, 0, stream>>>(offs, bsum, nblk);
    k_fill<<<dim3((E + 255) / 256, 5), 256, 0, stream>>>(EP, offs, cur, epay, E);

    // --- fused denominators + gather + residual + ReLU + LN (single pass) ---
    k_gather<<<(NJ + 7) / 8, 512, 0, stream>>>(offs, epay, as_cat,
                                               a_d, hs_cat, resb, bias_sum,
                                               gamma, beta, out, NJ);
}